// Round 1
// 344.167 us; speedup vs baseline: 1.0334x; 1.0334x over previous
//
#include <hip/hip_runtime.h>

// HeteroGNN on MI355X. Inputs/weights/output fp32 (per reference); intermediates bf16.
// Round 9: k_host/k_mega go to 512 threads/block (8 waves) with col-split MFMA waves.
// LDS footprint unchanged (39.4KB -> 4 blocks/CU) so occupancy doubles 16->32 waves/CU;
// the random-gather latency (the measured bottleneck: 9% HBM, 4% MFMA, 39% occ) gets
// 2x the outstanding loads. Wave (wr,wc) owns 16-row band x 64-col half; explicit
// barriers replace the old wave-private-band trick; g is written in-place over sAg.
//   k_pre  : weights->bf16 WT[n][k] | x->bf16 pools | bucket histogram
//   kb2    : bin scatter (in-block 275-prefix)  kb3: per-bucket CSR build
//   k_host : h=lrelu([mean(xfb nbrs)|xhb]@WT0_fh^T+b0); hT=h@WT1_l^T        (M=20000)
//   k_mega : h=lrelu([mean(xhb nbrs)|xfb]@WT0_hf^T+b0);
//            g=lrelu(h@WT1_r^T+mean(hT nbrs)+b1); out=g@WTo^T+bout          (M=200000)
// g_host dead in reference -> W1_fh_* unused.

#define N_HOST 20000
#define N_FLOW 200000
#define NEDGE  600000
#define D_IN   64
#define D_H    128
#define D_OUT  32
#define NSEG   (N_FLOW + N_HOST)
#define NBKT_F 196
#define NBKT_H 79
#define NBKT   (NBKT_F + NBKT_H)   // 275
#define NEB    586                 // ceil(1200000/2048)

typedef unsigned short u16;
typedef unsigned int   u32;
typedef short bf16x8 __attribute__((ext_vector_type(8)));
typedef float f32x4  __attribute__((ext_vector_type(4)));

__device__ __forceinline__ float bfh(u16 h) { return __uint_as_float(((u32)h) << 16); }
__device__ __forceinline__ u16 fbh(float f) {
    u32 u = __float_as_uint(f);
    return (u16)((u + 0x7fffu + ((u >> 16) & 1u)) >> 16);   // RNE
}
__device__ __forceinline__ u32 packbf(float x, float y) {
    return (u32)fbh(x) | ((u32)fbh(y) << 16);
}
__device__ __forceinline__ void acc8(float* a, uint4 u) {
    a[0] += __uint_as_float(u.x << 16);
    a[1] += __uint_as_float(u.x & 0xffff0000u);
    a[2] += __uint_as_float(u.y << 16);
    a[3] += __uint_as_float(u.y & 0xffff0000u);
    a[4] += __uint_as_float(u.z << 16);
    a[5] += __uint_as_float(u.z & 0xffff0000u);
    a[6] += __uint_as_float(u.w << 16);
    a[7] += __uint_as_float(u.w & 0xffff0000u);
}

// gather-mean of 16B chunks; neighbor indices from LDS window (fit) or global fallback.
// U = load batch width (outstanding loads per dependent round).
template <int U>
__device__ __forceinline__ uint4 gmean(const u16* __restrict__ pool, int rs, int coff,
                                       const int* __restrict__ gcsr,
                                       const int* __restrict__ lcsr, int st0, bool fit,
                                       int st, int en) {
    float a[8] = {0.f, 0.f, 0.f, 0.f, 0.f, 0.f, 0.f, 0.f};
    for (int e = st; e < en; e += U) {
        int n[U];
#pragma unroll
        for (int j = 0; j < U; j++)
            n[j] = (e + j < en) ? (fit ? lcsr[e + j - st0] : gcsr[e + j]) : -1;
        uint4 u[U];
#pragma unroll
        for (int j = 0; j < U; j++)
            u[j] = (n[j] >= 0) ? *(const uint4*)(pool + n[j] * rs + coff)
                               : make_uint4(0u, 0u, 0u, 0u);
#pragma unroll
        for (int j = 0; j < U; j++) acc8(a, u[j]);
    }
    float inv = (en > st) ? 1.f / (float)(en - st) : 0.f;
    uint4 o;
    o.x = packbf(a[0] * inv, a[1] * inv);
    o.y = packbf(a[2] * inv, a[3] * inv);
    o.z = packbf(a[4] * inv, a[5] * inv);
    o.w = packbf(a[6] * inv, a[7] * inv);
    return o;
}

// ---------------- k_pre: weights transpose | x->bf16 | bucket histogram ----------------
__global__ void k_pre(const float* __restrict__ W0_hf_l, const float* __restrict__ W0_hf_r,
                      const float* __restrict__ W0_fh_l, const float* __restrict__ W0_fh_r,
                      const float* __restrict__ W1_l, const float* __restrict__ W1_r,
                      const float* __restrict__ Wout,
                      u16* __restrict__ WT0_hf, u16* __restrict__ WT0_fh,
                      u16* __restrict__ WT1_l, u16* __restrict__ WT1_r,
                      u16* __restrict__ WTo,
                      const float* __restrict__ xf, const float* __restrict__ xh,
                      u16* __restrict__ xfb, u16* __restrict__ xhb,
                      const int* __restrict__ dst_hf, const int* __restrict__ dst_fh,
                      int* __restrict__ bcnt) {
    int b = blockIdx.x, t = threadIdx.x;
    if (b < 34) {
        u16 tmp[8];
        if (b < 32) {
            int e = (b & 7) * 2048 + t * 8;
            int n = e >> 7, k0 = e & 127;
            if (b < 8) {
#pragma unroll
                for (int j = 0; j < 8; j++) {
                    int k = k0 + j;
                    tmp[j] = fbh(k < 64 ? W0_hf_l[k * D_H + n] : W0_hf_r[(k - 64) * D_H + n]);
                }
                *(uint4*)(WT0_hf + n * 128 + k0) = *(uint4*)tmp;
            } else if (b < 16) {
#pragma unroll
                for (int j = 0; j < 8; j++) {
                    int k = k0 + j;
                    tmp[j] = fbh(k < 64 ? W0_fh_l[k * D_H + n] : W0_fh_r[(k - 64) * D_H + n]);
                }
                *(uint4*)(WT0_fh + n * 128 + k0) = *(uint4*)tmp;
            } else if (b < 24) {
#pragma unroll
                for (int j = 0; j < 8; j++) tmp[j] = fbh(W1_l[(k0 + j) * D_H + n]);
                *(uint4*)(WT1_l + n * 128 + k0) = *(uint4*)tmp;
            } else {
#pragma unroll
                for (int j = 0; j < 8; j++) tmp[j] = fbh(W1_r[(k0 + j) * D_H + n]);
                *(uint4*)(WT1_r + n * 128 + k0) = *(uint4*)tmp;
            }
        } else {
            int e = (b - 32) * 2048 + t * 8;
            int n = e >> 7, k0 = e & 127;
#pragma unroll
            for (int j = 0; j < 8; j++) tmp[j] = fbh(Wout[(k0 + j) * D_OUT + n]);
            *(uint4*)(WTo + n * 128 + k0) = *(uint4*)tmp;
        }
    } else if (b < 34 + 6875) {
        int q = (b - 34) * 256 + t;       // 8 floats per thread
        const int TF = (N_FLOW * D_IN) / 8;
        const int TT = TF + (N_HOST * D_IN) / 8;
        if (q >= TT) return;
        const float* src; u16* dst; int base;
        if (q < TF) { src = xf; dst = xfb; base = q * 8; }
        else        { src = xh; dst = xhb; base = (q - TF) * 8; }
        float4 f0 = *(const float4*)(src + base);
        float4 f1 = *(const float4*)(src + base + 4);
        uint4 o;
        o.x = packbf(f0.x, f0.y); o.y = packbf(f0.z, f0.w);
        o.z = packbf(f1.x, f1.y); o.w = packbf(f1.z, f1.w);
        *(uint4*)(dst + base) = o;
    } else {
        __shared__ int h[NBKT];
        for (int j = t; j < NBKT; j += 256) h[j] = 0;
        __syncthreads();
        int base = (b - 34 - 6875) * 2048;
#pragma unroll
        for (int i = 0; i < 8; i++) {
            int e = base + t + i * 256;
            if (e < 2 * NEDGE) {
                int bkt = (e < NEDGE) ? (dst_hf[e] >> 10)
                                      : (NBKT_F + (dst_fh[e - NEDGE] >> 8));
                atomicAdd(&h[bkt], 1);
            }
        }
        __syncthreads();
        for (int j = t; j < NBKT; j += 256)
            if (h[j]) atomicAdd(&bcnt[j], h[j]);
    }
}

// ---------------- kb2: bin scatter (in-block prefix of bcnt) ----------------
__global__ void kb2(const int* __restrict__ src_hf, const int* __restrict__ dst_hf,
                    const int* __restrict__ src_fh, const int* __restrict__ dst_fh,
                    const int* __restrict__ bcnt, int* __restrict__ bcur,
                    int2* __restrict__ binE) {
    __shared__ int sp[512];    // becomes exclusive bucket base
    __shared__ int lh[NBKT];
    __shared__ int lb[NBKT];
    int t = threadIdx.x;
    int o1 = (t < NBKT) ? bcnt[t] : 0;
    int o2 = (t + 256 < NBKT) ? bcnt[t + 256] : 0;
    sp[t] = o1; sp[t + 256] = o2;
    for (int j = t; j < NBKT; j += 256) lh[j] = 0;
    __syncthreads();
    for (int d = 1; d < 512; d <<= 1) {
        int a0 = (t >= d) ? sp[t - d] : 0;
        int a1 = sp[t + 256 - d];
        __syncthreads();
        sp[t] += a0; sp[t + 256] += a1;
        __syncthreads();
    }
    sp[t] -= o1; sp[t + 256] -= o2;   // exclusive
    __syncthreads();
    int base = blockIdx.x * 2048;
    int mybkt[8], myrank[8], mysrc[8], mydst[8];
#pragma unroll
    for (int i = 0; i < 8; i++) {
        int e = base + t + i * 256;
        mybkt[i] = -1;
        if (e < 2 * NEDGE) {
            int s, d;
            if (e < NEDGE) { s = src_hf[e]; d = dst_hf[e]; }
            else           { s = src_fh[e - NEDGE]; d = dst_fh[e - NEDGE] + N_FLOW; }
            int bkt = (d < N_FLOW) ? (d >> 10) : (NBKT_F + ((d - N_FLOW) >> 8));
            mybkt[i] = bkt; mysrc[i] = s; mydst[i] = d;
            myrank[i] = atomicAdd(&lh[bkt], 1);
        }
    }
    __syncthreads();
    for (int j = t; j < NBKT; j += 256)
        lb[j] = lh[j] ? atomicAdd(&bcur[j], lh[j]) : 0;
    __syncthreads();
#pragma unroll
    for (int i = 0; i < 8; i++) {
        if (mybkt[i] >= 0) {
            int pos = sp[mybkt[i]] + lb[mybkt[i]] + myrank[i];
            binE[pos] = make_int2(mysrc[i], mydst[i]);
        }
    }
}

// ---------------- kb3: per-bucket CSR (in-block prefix of bcnt) ----------------
__global__ __launch_bounds__(256) void kb3(const int2* __restrict__ binE,
                                           const int* __restrict__ bcnt,
                                           int* __restrict__ off, int* __restrict__ csr) {
    __shared__ int sp[512];
    __shared__ int deg[1024];
    __shared__ int ts[256];
    int b = blockIdx.x, t = threadIdx.x;
    sp[t] = (t < NBKT) ? bcnt[t] : 0;
    sp[t + 256] = (t + 256 < NBKT) ? bcnt[t + 256] : 0;
    __syncthreads();
    for (int d = 1; d < 512; d <<= 1) {
        int a0 = (t >= d) ? sp[t - d] : 0;
        int a1 = sp[t + 256 - d];
        __syncthreads();
        sp[t] += a0; sp[t + 256] += a1;
        __syncthreads();
    }
    int e0 = (b == 0) ? 0 : sp[b - 1];
    int e1 = sp[b];
    int nbase, ncnt;
    if (b < NBKT_F) { nbase = b << 10; ncnt = min(1024, N_FLOW - nbase); }
    else { nbase = N_FLOW + ((b - NBKT_F) << 8); ncnt = min(256, NSEG - nbase); }
    for (int i = t; i < 1024; i += 256) deg[i] = 0;
    __syncthreads();
    for (int e = e0 + t; e < e1; e += 256) {
        int2 p = binE[e];
        atomicAdd(&deg[p.y - nbase], 1);
    }
    __syncthreads();
    int loc[4]; int s = 0;
#pragma unroll
    for (int j = 0; j < 4; j++) { loc[j] = s; s += deg[t * 4 + j]; }
    ts[t] = s;
    __syncthreads();
    for (int d = 1; d < 256; d <<= 1) {
        int x = (t >= d) ? ts[t - d] : 0;
        __syncthreads();
        ts[t] += x;
        __syncthreads();
    }
    int base2 = e0 + ts[t] - s;
    int dsave[4];
#pragma unroll
    for (int j = 0; j < 4; j++) dsave[j] = deg[t * 4 + j];
    __syncthreads();
#pragma unroll
    for (int j = 0; j < 4; j++) {
        int idx = t * 4 + j;
        int st = base2 + loc[j];
        deg[idx] = st;
        if (idx < ncnt) off[nbase + idx] = st + dsave[j];   // segment END
    }
    __syncthreads();
    for (int e = e0 + t; e < e1; e += 256) {
        int2 p = binE[e];
        int r = atomicAdd(&deg[p.y - nbase], 1);
        csr[r] = p.x;
    }
}

// ---------------- k_host: G2+G3 fused (M=20000), 512 thr, col-split waves ----------------
__global__ __launch_bounds__(512, 4) void k_host(
    const u16* __restrict__ xfb, const u16* __restrict__ xhb,
    const int* __restrict__ off, const int* __restrict__ csr,
    const u16* __restrict__ WT0, const float* __restrict__ b0,
    const u16* __restrict__ WT1l, u16* __restrict__ hT, int M) {
    __shared__ __align__(16) u16 sA[64 * 136];
    __shared__ int sOff[72];
    __shared__ int sCsr[2560];
    const int t = threadIdx.x;
    const int m0 = blockIdx.x * 64;
    if (t < 65) {
        int idx = N_FLOW + m0 - 1 + t;
        sOff[t] = off[min(idx, NSEG - 1)];
    }
    // direct half: xhb row, k in [64,128)  — 512 chunks, 1/thread
    {
        int r = t >> 3, c = t & 7;
        int row = m0 + r;
        uint4 v = make_uint4(0u, 0u, 0u, 0u);
        if (row < M) v = *(const uint4*)(xhb + row * 64 + c * 8);
        *(uint4*)(&sA[r * 136 + 64 + c * 8]) = v;
    }
    __syncthreads();
    int st0 = sOff[0];
    int win = sOff[64] - st0;
    bool fit = (win <= 2560);
    if (fit) for (int e = t; e < win; e += 512) sCsr[e] = csr[st0 + e];
    __syncthreads();
    // gather half: mean(xfb nbrs), k in [0,64) — deg~30, batch 8 loads/round
    {
        int r = t >> 3, c = t & 7;
        int row = m0 + r;
        uint4 o = make_uint4(0u, 0u, 0u, 0u);
        if (row < M) o = gmean<8>(xfb, 64, c * 8, csr, sCsr, st0, fit, sOff[r], sOff[r + 1]);
        *(uint4*)(&sA[r * 136 + c * 8]) = o;
    }
    __syncthreads();
    const int w = t >> 6, wr = w >> 1, wc = w & 1;
    const int ln = t & 63, l15 = ln & 15, quad = ln >> 4;
    const u16* pA = sA + (wr * 16 + l15) * 136 + quad * 8;
    const u16* pB0 = WT0 + wc * 8192 + l15 * 128 + quad * 8;
    f32x4 acc[4];
#pragma unroll
    for (int tt = 0; tt < 4; tt++) acc[tt] = (f32x4){0.f, 0.f, 0.f, 0.f};
#pragma unroll
    for (int s = 0; s < 4; s++) {
        bf16x8 a = *(const bf16x8*)(pA + s * 32);
#pragma unroll
        for (int tt = 0; tt < 4; tt++) {
            bf16x8 b = *(const bf16x8*)(pB0 + tt * 2048 + s * 32);
            acc[tt] = __builtin_amdgcn_mfma_f32_16x16x32_bf16(a, b, acc[tt], 0, 0, 0);
        }
    }
    __syncthreads();   // all phase-A reads of sA done before h overwrites it
#pragma unroll
    for (int tt = 0; tt < 4; tt++) {
        int col = wc * 64 + tt * 16 + l15;
        float bv = b0[col];
#pragma unroll
        for (int i = 0; i < 4; i++) {
            int rl = wr * 16 + quad * 4 + i;
            float v = acc[tt][i] + bv;
            v = v > 0.f ? v : 0.01f * v;
            sA[rl * 136 + col] = fbh(v);
        }
    }
    __syncthreads();   // h complete (both col-half waves) before phase B reads
    const u16* pB1 = WT1l + wc * 8192 + l15 * 128 + quad * 8;
    f32x4 accB[4];
#pragma unroll
    for (int tt = 0; tt < 4; tt++) accB[tt] = (f32x4){0.f, 0.f, 0.f, 0.f};
#pragma unroll
    for (int s = 0; s < 4; s++) {
        bf16x8 a = *(const bf16x8*)(pA + s * 32);
#pragma unroll
        for (int tt = 0; tt < 4; tt++) {
            bf16x8 b = *(const bf16x8*)(pB1 + tt * 2048 + s * 32);
            accB[tt] = __builtin_amdgcn_mfma_f32_16x16x32_bf16(a, b, accB[tt], 0, 0, 0);
        }
    }
#pragma unroll
    for (int tt = 0; tt < 4; tt++) {
        int col = wc * 64 + tt * 16 + l15;
#pragma unroll
        for (int i = 0; i < 4; i++) {
            int row = m0 + wr * 16 + quad * 4 + i;
            if (row < M) hT[row * D_H + col] = fbh(accB[tt][i]);
        }
    }
}

// ---------------- k_mega: G1+G4 fused (M=200000, no tail), 512 thr ----------------
__global__ __launch_bounds__(512, 8) void k_mega(
    const u16* __restrict__ xfb, const u16* __restrict__ xhb,
    const int* __restrict__ off, const int* __restrict__ csr,
    const u16* __restrict__ hT,
    const u16* __restrict__ WT0, const float* __restrict__ b0,
    const u16* __restrict__ WT1r, const float* __restrict__ b1,
    const u16* __restrict__ WTo, const float* __restrict__ bout,
    float* __restrict__ OUT) {
    __shared__ __align__(16) u16 sA[64 * 136];    // A0 tile -> h band
    __shared__ __align__(16) u16 sAg[64 * 136];   // gathered mean(hT) tile -> g band
    __shared__ int sOff[72];
    __shared__ int sCsr[1024];
    const int t = threadIdx.x;
    const int m0 = blockIdx.x * 64;
    if (t < 65) {
        int idx = m0 - 1 + t;
        sOff[t] = (idx < 0) ? 0 : off[idx];
    }
    // direct half: xfb row, k in [64,128) — 512 chunks, 1/thread
    {
        int r = t >> 3, c = t & 7;
        uint4 v = *(const uint4*)(xfb + (m0 + r) * 64 + c * 8);
        *(uint4*)(&sA[r * 136 + 64 + c * 8]) = v;
    }
    __syncthreads();
    int st0 = sOff[0];
    int win = sOff[64] - st0;
    bool fit = (win <= 1024);
    if (fit) for (int e = t; e < win; e += 512) sCsr[e] = csr[st0 + e];
    __syncthreads();
    // A0 gather half: mean(xhb nbrs), k in [0,64) — 512 tasks
    {
        int r = t >> 3, c = t & 7;
        uint4 o = gmean<4>(xhb, 64, c * 8, csr, sCsr, st0, fit, sOff[r], sOff[r + 1]);
        *(uint4*)(&sA[r * 136 + c * 8]) = o;
    }
    // agg tile: mean(hT nbrs), 128d — 1024 tasks, 2/thread
#pragma unroll
    for (int i = 0; i < 2; i++) {
        int q = t + i * 512;
        int r = q >> 4, c = q & 15;
        uint4 o = gmean<4>(hT, 128, c * 8, csr, sCsr, st0, fit, sOff[r], sOff[r + 1]);
        *(uint4*)(&sAg[r * 136 + c * 8]) = o;
    }
    __syncthreads();
    const int w = t >> 6, wr = w >> 1, wc = w & 1;   // wave = (row-band, col-half)
    const int ln = t & 63, l15 = ln & 15, quad = ln >> 4;
    const u16* pA = sA + (wr * 16 + l15) * 136 + quad * 8;
    const u16* pB0 = WT0 + wc * 8192 + l15 * 128 + quad * 8;
    f32x4 acc[4];
#pragma unroll
    for (int tt = 0; tt < 4; tt++) acc[tt] = (f32x4){0.f, 0.f, 0.f, 0.f};
#pragma unroll
    for (int s = 0; s < 4; s++) {
        bf16x8 a = *(const bf16x8*)(pA + s * 32);
#pragma unroll
        for (int tt = 0; tt < 4; tt++) {
            bf16x8 b = *(const bf16x8*)(pB0 + tt * 2048 + s * 32);
            acc[tt] = __builtin_amdgcn_mfma_f32_16x16x32_bf16(a, b, acc[tt], 0, 0, 0);
        }
    }
    __syncthreads();   // all phase-A reads of sA done before h overwrites it
    // epilogue1: h = lrelu(acc + b0) -> sA band (cols wc*64 ..)
#pragma unroll
    for (int tt = 0; tt < 4; tt++) {
        int col = wc * 64 + tt * 16 + l15;
        float bv = b0[col];
#pragma unroll
        for (int i = 0; i < 4; i++) {
            int rl = wr * 16 + quad * 4 + i;
            float v = acc[tt][i] + bv;
            v = v > 0.f ? v : 0.01f * v;
            sA[rl * 136 + col] = fbh(v);
        }
    }
    __syncthreads();   // h complete before phase B reads full rows
    // phase B: h @ WT1r^T
    const u16* pB1 = WT1r + wc * 8192 + l15 * 128 + quad * 8;
    f32x4 accB[4];
#pragma unroll
    for (int tt = 0; tt < 4; tt++) accB[tt] = (f32x4){0.f, 0.f, 0.f, 0.f};
#pragma unroll
    for (int s = 0; s < 4; s++) {
        bf16x8 a = *(const bf16x8*)(pA + s * 32);
#pragma unroll
        for (int tt = 0; tt < 4; tt++) {
            bf16x8 b = *(const bf16x8*)(pB1 + tt * 2048 + s * 32);
            accB[tt] = __builtin_amdgcn_mfma_f32_16x16x32_bf16(a, b, accB[tt], 0, 0, 0);
        }
    }
    // epilogue2: g = lrelu(accB + agg + b1) -> in-place over sAg (same thread r/w per elem)
#pragma unroll
    for (int tt = 0; tt < 4; tt++) {
        int col = wc * 64 + tt * 16 + l15;
        float bv = b1[col];
#pragma unroll
        for (int i = 0; i < 4; i++) {
            int rl = wr * 16 + quad * 4 + i;
            float v = accB[tt][i] + bfh(sAg[rl * 136 + col]) + bv;
            v = v > 0.f ? v : 0.01f * v;
            sAg[rl * 136 + col] = fbh(v);
        }
    }
    __syncthreads();   // g complete before phase C reads full rows
    // phase C: out = g @ WTo^T + bout  (each wave: 16-row band x 16-col tile wc)
    const u16* pG = sAg + (wr * 16 + l15) * 136 + quad * 8;
    const u16* pBo = WTo + wc * 2048 + l15 * 128 + quad * 8;
    f32x4 acc2 = (f32x4){0.f, 0.f, 0.f, 0.f};
#pragma unroll
    for (int s = 0; s < 4; s++) {
        bf16x8 g = *(const bf16x8*)(pG + s * 32);
        bf16x8 b = *(const bf16x8*)(pBo + s * 32);
        acc2 = __builtin_amdgcn_mfma_f32_16x16x32_bf16(g, b, acc2, 0, 0, 0);
    }
    {
        int col = wc * 16 + l15;
        float bv = bout[col];
#pragma unroll
        for (int i = 0; i < 4; i++) {
            int row = m0 + wr * 16 + quad * 4 + i;
            OUT[row * D_OUT + col] = acc2[i] + bv;
        }
    }
}

extern "C" void kernel_launch(void* const* d_in, const int* in_sizes, int n_in,
                              void* d_out, int out_size, void* d_ws, size_t ws_size,
                              hipStream_t stream) {
    const float* x_host  = (const float*)d_in[0];
    const float* x_flow  = (const float*)d_in[1];
    const int* src_hf  = (const int*)d_in[2];
    const int* dst_hf  = (const int*)d_in[3];
    const int* src_fh  = (const int*)d_in[4];
    const int* dst_fh  = (const int*)d_in[5];
    const float* W0_hf_l = (const float*)d_in[6];
    const float* W0_hf_r = (const float*)d_in[7];
    const float* b0_hf   = (const float*)d_in[8];
    const float* W0_fh_l = (const float*)d_in[9];
    const float* W0_fh_r = (const float*)d_in[10];
    const float* b0_fh   = (const float*)d_in[11];
    const float* W1_hf_l = (const float*)d_in[12];
    const float* W1_hf_r = (const float*)d_in[13];
    const float* b1_hf   = (const float*)d_in[14];
    const float* W_out   = (const float*)d_in[18];
    const float* b_out   = (const float*)d_in[19];
    float* out = (float*)d_out;

    // workspace layout (bytes), all disjoint, total ~48.7 MB
    char* ws = (char*)d_ws;
    int*  off    = (int*)(ws + 0);             //   880,000
    int*  csr    = (int*)(ws + 880000);        // 4,800,000
    u16*  hT     = (u16*)(ws + 5680000);       //  5,120,000
    u16*  xfb    = (u16*)(ws + 10800000);      // 25,600,000
    u16*  xhb    = (u16*)(ws + 36400000);      //  2,560,000
    int2* binE   = (int2*)(ws + 38960000);     //  9,600,000
    int*  bcnt   = (int*)(ws + 48560000);      //  1,280
    int*  bcur   = (int*)(ws + 48561280);      //  1,280
    u16*  WT0_hf = (u16*)(ws + 48562560);      //  32,768
    u16*  WT0_fh = (u16*)(ws + 48595328);      //  32,768
    u16*  WT1_l  = (u16*)(ws + 48628096);      //  32,768
    u16*  WT1_r  = (u16*)(ws + 48660864);      //  32,768
    u16*  WTo    = (u16*)(ws + 48693632);      //   8,192

    hipMemsetAsync(bcnt, 0, 2560, stream);     // bcnt + bcur
    k_pre<<<34 + 6875 + NEB, 256, 0, stream>>>(
        W0_hf_l, W0_hf_r, W0_fh_l, W0_fh_r, W1_hf_l, W1_hf_r, W_out,
        WT0_hf, WT0_fh, WT1_l, WT1_r, WTo,
        x_flow, x_host, xfb, xhb, dst_hf, dst_fh, bcnt);
    kb2<<<NEB, 256, 0, stream>>>(src_hf, dst_hf, src_fh, dst_fh, bcnt, bcur, binE);
    kb3<<<NBKT, 256, 0, stream>>>(binE, bcnt, off, csr);
    k_host<<<313, 512, 0, stream>>>(xfb, xhb, off, csr, WT0_fh, b0_fh, WT1_l, hT, N_HOST);
    k_mega<<<3125, 512, 0, stream>>>(xfb, xhb, off, csr, hT, WT0_hf, b0_hf,
                                     WT1_r, b1_hf, WTo, b_out, out);
}